// Round 11
// baseline (311.927 us; speedup 1.0000x reference)
//
#include <hip/hip_runtime.h>
#include <math.h>

#define T_DIM 2048
#define B_DIM 16
#define H_DIM 512
#define NKB   (H_DIM / 32)   // 16 k-blocks of 32
// out: results [T,B,2H] (33,554,432 f32) then attn [B,T,T] (67,108,864 f32)
// ws (ushort = fp16 bits), arrays TILED: tile(rowblk,kblk) = 8KB as [g(4)][row(128)][8]
//   Xh @0 (33.5MB), PML (float2 [B*T][16], 4MB) @16Mi elems, Qh @32Mi elems, Wth @64Mi elems.

typedef _Float16 f16x8 __attribute__((ext_vector_type(8)));
typedef float f32x4 __attribute__((ext_vector_type(4)));

__device__ __forceinline__ unsigned short h_bits(_Float16 h) {
    unsigned short u; __builtin_memcpy(&u, &h, 2); return u;
}

__device__ __forceinline__ size_t tile_off(int rowblk, int kblk) {
    return ((size_t)rowblk * NKB + kblk) * 4096;   // 4096 ushorts = 8KB per tile
}
__device__ __forceinline__ size_t tiled_idx(int r, int c) {
    return tile_off(r >> 7, c >> 5) + (size_t)((c >> 3) & 3) * 1024 + (size_t)(r & 127) * 8 + (c & 7);
}

// ---------- Kernel 1: results copy + X -> fp16 (tiled, batch-major) ----------
__global__ __launch_bounds__(256) void k_prep(const float* __restrict__ X,
                                              const float* __restrict__ RC,
                                              float* __restrict__ out,
                                              unsigned short* __restrict__ Xh) {
    int i = blockIdx.x * 256 + threadIdx.x;
    int row = i >> 6;                 // t*B + b
    int h0 = (i & 63) * 8;
    int t = row >> 4;
    int b = row & 15;
    const float* xp = X + (size_t)row * H_DIM + h0;
    float4 v0 = *(const float4*)xp;
    float4 v1 = *(const float4*)(xp + 4);
    float* op = out + (size_t)row * (2 * H_DIM) + h0;
    *(float4*)op = v0;
    *(float4*)(op + 4) = v1;
    const float* cp = RC + (size_t)row * H_DIM + h0;
    float4 c0 = *(const float4*)cp;
    float4 c1 = *(const float4*)(cp + 4);
    if (t < 2) { c0 = v0; c1 = v1; }
    *(float4*)(op + H_DIM) = c0;
    *(float4*)(op + H_DIM + 4) = c1;
    float xs[8] = {v0.x, v0.y, v0.z, v0.w, v1.x, v1.y, v1.z, v1.w};
    unsigned int hw[4];
#pragma unroll
    for (int e = 0; e < 4; ++e) {
        _Float16 a = (_Float16)xs[2 * e], bb = (_Float16)xs[2 * e + 1];
        hw[e] = (unsigned int)h_bits(a) | ((unsigned int)h_bits(bb) << 16);
    }
    int r = b * T_DIM + t;            // batch-major row index
    *(uint4*)(Xh + tiled_idx(r, h0)) = make_uint4(hw[0], hw[1], hw[2], hw[3]);
}

// ---------- Kernel 2: W -> transposed fp16, tiled [n][k] ----------
__global__ __launch_bounds__(256) void k_split_w(const float* __restrict__ W,
                                                 unsigned short* __restrict__ Wth) {
    int i = blockIdx.x * 256 + threadIdx.x;
    int n = i & 511;
    int k0 = (i >> 9) * 8;
    unsigned int hw[4];
#pragma unroll
    for (int e = 0; e < 4; ++e) {
        _Float16 h0 = (_Float16)W[(size_t)(k0 + 2 * e) * H_DIM + n];
        _Float16 h1 = (_Float16)W[(size_t)(k0 + 2 * e + 1) * H_DIM + n];
        hw[e] = (unsigned int)h_bits(h0) | ((unsigned int)h_bits(h1) << 16);
    }
    *(uint4*)(Wth + tiled_idx(n, k0)) = make_uint4(hw[0], hw[1], hw[2], hw[3]);
}

// ---------- staging: half of a pre-tiled 8KB tile -> LDS, linear coalesced copy ----------
__device__ __forceinline__ void stage_half(const unsigned short* __restrict__ src_tile,
                                           unsigned short* lds_base, int lane, int h) {
#pragma unroll
    for (int c = 0; c < 4; ++c) {
        const int ch = h * 4 + c;
        __builtin_amdgcn_global_load_lds(
            (const __attribute__((address_space(1))) void*)(src_tile + ch * 512 + lane * 8),
            (__attribute__((address_space(3))) void*)(lds_base + ch * 512),
            16, 0, 0);
    }
}

// ---------- Kernel 3: Q = X @ W, single-pass fp16 MFMA, BK=64 (R10-proven) ----------
__global__ __launch_bounds__(256) void k_qgemm_mfma(const unsigned short* __restrict__ Xh,
                                                    const unsigned short* __restrict__ Wth,
                                                    unsigned short* __restrict__ Qh) {
    __shared__ __align__(16) unsigned short Ah[2][4][128][8], Bh[2][4][128][8];
    const int bid = blockIdx.x;                       // 1024 = 8 * 128
    const int swz = (bid & 7) * 128 + (bid >> 3);     // bijective
    const int mblk = swz >> 2, nblk = swz & 3;
    const int m0 = mblk * 128, n0 = nblk * 128;
    const int tid = threadIdx.x, lane = tid & 63, w = tid >> 6;
    const int t_off = (w >> 1) * 64, s_off = (w & 1) * 64;
    const int l15 = lane & 15, lg = lane >> 4;
    f32x4 acc[4][4] = {};

    for (int ksp = 0; ksp < NKB / 2; ++ksp) {
        if (ksp) __syncthreads();
        if (w < 2) {
            stage_half(Xh + tile_off(mblk, 2 * ksp),     &Ah[0][0][0][0], lane, w);
            stage_half(Xh + tile_off(mblk, 2 * ksp + 1), &Ah[1][0][0][0], lane, w);
        } else {
            stage_half(Wth + tile_off(nblk, 2 * ksp),     &Bh[0][0][0][0], lane, w - 2);
            stage_half(Wth + tile_off(nblk, 2 * ksp + 1), &Bh[1][0][0][0], lane, w - 2);
        }
        __syncthreads();

#pragma unroll
        for (int kk = 0; kk < 2; ++kk) {
            f16x8 ah[4], bh[4];
#pragma unroll
            for (int i2 = 0; i2 < 4; ++i2)
                ah[i2] = *(const f16x8*)&Ah[kk][lg][t_off + i2 * 16 + l15][0];
#pragma unroll
            for (int j = 0; j < 4; ++j)
                bh[j] = *(const f16x8*)&Bh[kk][lg][s_off + j * 16 + l15][0];
#pragma unroll
            for (int i2 = 0; i2 < 4; ++i2)
#pragma unroll
                for (int j = 0; j < 4; ++j)
                    acc[i2][j] = __builtin_amdgcn_mfma_f32_16x16x32_f16(ah[i2], bh[j], acc[i2][j], 0, 0, 0);
        }
    }

    // scatter epilogue (proven pattern), hi-only fp16 output
#pragma unroll
    for (int i2 = 0; i2 < 4; ++i2)
#pragma unroll
        for (int j = 0; j < 4; ++j)
#pragma unroll
            for (int r = 0; r < 4; ++r) {
                int R = m0 + t_off + i2 * 16 + lg * 4 + r;
                int C = n0 + s_off + j * 16 + l15;
                _Float16 qh = (_Float16)acc[i2][j][r];
                Qh[tiled_idx(R, C)] = h_bits(qh);
            }
}

// ---------- Kernel 4: scores + per-tile softmax partials (m,l) ----------
__global__ __launch_bounds__(256) void k_scores_mfma(const unsigned short* __restrict__ Qh,
                                                     const unsigned short* __restrict__ Xh,
                                                     float* __restrict__ attn,
                                                     float2* __restrict__ PML) {
    // 2176 live blocks = 16 batches x 136 triangle tile-pairs; 2176 = 8 * 272
    const int bid = blockIdx.x;
    const int swz = (bid & 7) * 272 + (bid >> 3);     // bijective XCD chunking
    const int b = swz / 136;
    const int r = swz - b * 136;
    int ti = (int)((sqrtf(8.f * (float)r + 1.f) - 1.f) * 0.5f);
    while ((ti + 1) * (ti + 2) / 2 <= r) ++ti;
    while (ti * (ti + 1) / 2 > r) --ti;
    const int si = r - ti * (ti + 1) / 2;             // si <= ti
    const int t0 = ti * 128, s0 = si * 128;

    __shared__ __align__(16) unsigned short Ah[2][4][128][8], Bh[2][4][128][8];
    __shared__ float sm_m[4][64], sm_l[4][64];
    const int tid = threadIdx.x, lane = tid & 63, w = tid >> 6;
    const int t_off = (w >> 1) * 64, s_off = (w & 1) * 64;
    const int l15 = lane & 15, lg = lane >> 4;
    const int ablk = b * (T_DIM / 128) + ti;
    const int bblk = b * (T_DIM / 128) + si;
    f32x4 acc[4][4] = {};

    for (int ksp = 0; ksp < NKB / 2; ++ksp) {
        if (ksp) __syncthreads();
        if (w < 2) {
            stage_half(Qh + tile_off(ablk, 2 * ksp),     &Ah[0][0][0][0], lane, w);
            stage_half(Qh + tile_off(ablk, 2 * ksp + 1), &Ah[1][0][0][0], lane, w);
        } else {
            stage_half(Xh + tile_off(bblk, 2 * ksp),     &Bh[0][0][0][0], lane, w - 2);
            stage_half(Xh + tile_off(bblk, 2 * ksp + 1), &Bh[1][0][0][0], lane, w - 2);
        }
        __syncthreads();

#pragma unroll
        for (int kk = 0; kk < 2; ++kk) {
            f16x8 ah[4], bh[4];
#pragma unroll
            for (int i2 = 0; i2 < 4; ++i2)
                ah[i2] = *(const f16x8*)&Ah[kk][lg][t_off + i2 * 16 + l15][0];
#pragma unroll
            for (int j = 0; j < 4; ++j)
                bh[j] = *(const f16x8*)&Bh[kk][lg][s_off + j * 16 + l15][0];
#pragma unroll
            for (int i2 = 0; i2 < 4; ++i2)
#pragma unroll
                for (int j = 0; j < 4; ++j)
                    acc[i2][j] = __builtin_amdgcn_mfma_f32_16x16x32_f16(ah[i2], bh[j], acc[i2][j], 0, 0, 0);
        }
    }

    // ---- store raw scores + per-row (m,l) over this tile's valid cols ----
    float* base = attn + (size_t)b * T_DIM * T_DIM;
#pragma unroll
    for (int i2 = 0; i2 < 4; ++i2)
#pragma unroll
        for (int rr = 0; rr < 4; ++rr) {
            const int t = t0 + t_off + i2 * 16 + lg * 4 + rr;
            float vj[4];
            bool ok[4];
            float mloc = -1e30f;
#pragma unroll
            for (int j = 0; j < 4; ++j) {
                const int s = s0 + s_off + j * 16 + l15;
                vj[j] = acc[i2][j][rr];
                ok[j] = (s < t) && (t >= 2);
                base[(size_t)t * T_DIM + s] = vj[j];
                if (ok[j]) mloc = fmaxf(mloc, vj[j]);
            }
            // 16-lane group reduce (lanes share lg; xor<16 stays in group)
#pragma unroll
            for (int off = 1; off <= 8; off <<= 1)
                mloc = fmaxf(mloc, __shfl_xor(mloc, off));
            float lloc = 0.f;
#pragma unroll
            for (int j = 0; j < 4; ++j)
                if (ok[j]) lloc += expf(vj[j] - mloc);
#pragma unroll
            for (int off = 1; off <= 8; off <<= 1)
                lloc += __shfl_xor(lloc, off);
            if (l15 == 0) {
                const int lr = i2 * 16 + lg * 4 + rr;   // 0..63 within wave's rows
                sm_m[w][lr] = mloc;
                sm_l[w][lr] = lloc;
            }
        }
    __syncthreads();
    // merge s-halves (waves 0&1 rows 0-63, waves 2&3 rows 64-127), write partials
    if (tid < 128) {
        const int w0 = (tid >> 6) * 2;
        const int lr = tid & 63;
        float m1 = sm_m[w0][lr], l1 = sm_l[w0][lr];
        float m2 = sm_m[w0 + 1][lr], l2 = sm_l[w0 + 1][lr];
        float M = fmaxf(m1, m2);
        float L = l1 * expf(m1 - M) + l2 * expf(m2 - M);
        PML[(size_t)(b * T_DIM + t0 + tid) * 16 + si] = make_float2(M, L);
    }
}

// ---------- Kernel 5: softmax normalize (partials pre-merged; single R/W pass) ----------
__global__ __launch_bounds__(256) void k_softmax(float* __restrict__ attn,
                                                 const float2* __restrict__ PML) {
    const int row = blockIdx.x;
    const int t = row & (T_DIM - 1);
    float* p = attn + (size_t)row * T_DIM;
    const int tid = threadIdx.x;
    const int n = (t >= 2) ? t : 0;

    if (n == 0) {
        const float4 z = {0.f, 0.f, 0.f, 0.f};
        for (int s = tid * 4; s < T_DIM; s += 1024) *(float4*)&p[s] = z;
        return;
    }

    // merge the (ti+1) tile partials: lanes 0..15 load (sentinel elsewhere),
    // full 64-lane butterfly (sentinel = merge identity) -> all lanes converge
    const int ti = t >> 7;
    const int ln = tid & 63;
    float m = -1e30f, l = 0.f;
    if (ln <= ti) {
        float2 pm = PML[(size_t)row * 16 + ln];
        m = pm.x; l = pm.y;
    }
#pragma unroll
    for (int off = 1; off <= 32; off <<= 1) {
        float mo = __shfl_xor(m, off);
        float lo = __shfl_xor(l, off);
        float M = fmaxf(m, mo);
        l = l * expf(m - M) + lo * expf(mo - M);
        m = M;
    }
    const float inv = 1.f / l;

    // write pass: probs for s < n, zeros elsewhere
    for (int s = tid * 4; s < T_DIM; s += 1024) {
        float4 o = {0.f, 0.f, 0.f, 0.f};
        if (s + 3 < n) {
            float4 v = *(float4*)&p[s];
            o.x = expf(v.x - m) * inv;
            o.y = expf(v.y - m) * inv;
            o.z = expf(v.z - m) * inv;
            o.w = expf(v.w - m) * inv;
        } else if (s < n) {
            float tmp[4] = {0.f, 0.f, 0.f, 0.f};
            for (int j = 0; j < 4; ++j)
                if (s + j < n) tmp[j] = expf(p[s + j] - m) * inv;
            o.x = tmp[0]; o.y = tmp[1]; o.z = tmp[2]; o.w = tmp[3];
        }
        *(float4*)&p[s] = o;
    }
}

extern "C" void kernel_launch(void* const* d_in, const int* in_sizes, int n_in,
                              void* d_out, int out_size, void* d_ws, size_t ws_size,
                              hipStream_t stream) {
    const float* inputs   = (const float*)d_in[0];   // [T,B,H]
    const float* rand_ctx = (const float*)d_in[1];   // [T,B,H]
    const float* W        = (const float*)d_in[2];   // [H,H]
    float* out  = (float*)d_out;
    float* attn = out + (size_t)T_DIM * B_DIM * 2 * H_DIM;

    unsigned short* Xh  = (unsigned short*)d_ws;
    float2*         PML = (float2*)(Xh + (size_t)16777216);   // old Xl slot, 4MB
    unsigned short* Qh  = Xh + (size_t)33554432;
    unsigned short* Wth = Xh + (size_t)67108864;

    k_prep<<<dim3(T_DIM * B_DIM * 64 / 256), dim3(256), 0, stream>>>(
        inputs, rand_ctx, out, Xh);

    k_split_w<<<dim3(128), dim3(256), 0, stream>>>(W, Wth);

    k_qgemm_mfma<<<dim3(1024), dim3(256), 0, stream>>>(Xh, Wth, Qh);

    k_scores_mfma<<<dim3(2176), dim3(256), 0, stream>>>(Qh, Xh, attn, PML);

    k_softmax<<<dim3(B_DIM * T_DIM), dim3(256), 0, stream>>>(attn, PML);
}

// Round 12
// 308.467 us; speedup vs baseline: 1.0112x; 1.0112x over previous
//
#include <hip/hip_runtime.h>
#include <math.h>

#define T_DIM 2048
#define B_DIM 16
#define H_DIM 512
#define NKB   (H_DIM / 32)   // 16 k-blocks of 32
// out: results [T,B,2H] (33,554,432 f32) then attn [B,T,T] (67,108,864 f32)
// ws (ushort = fp16 bits), arrays TILED: tile(rowblk,kblk) = 8KB as [g(4)][row(128)][8]
// — byte-identical to the LDS image, staging is a linear coalesced copy.
//   Xh @0 (32MB), Qh @32Mi elems (32MB), Wth @64Mi elems (512KB).

typedef _Float16 f16x8 __attribute__((ext_vector_type(8)));
typedef float f32x4 __attribute__((ext_vector_type(4)));

__device__ __forceinline__ unsigned short h_bits(_Float16 h) {
    unsigned short u; __builtin_memcpy(&u, &h, 2); return u;
}

__device__ __forceinline__ size_t tile_off(int rowblk, int kblk) {
    return ((size_t)rowblk * NKB + kblk) * 4096;   // 4096 ushorts = 8KB per tile
}
__device__ __forceinline__ size_t tiled_idx(int r, int c) {
    return tile_off(r >> 7, c >> 5) + (size_t)((c >> 3) & 3) * 1024 + (size_t)(r & 127) * 8 + (c & 7);
}

// ---------- Kernel 1: results copy + X -> fp16 (tiled) ; tail blocks: W transpose ----------
__global__ __launch_bounds__(256) void k_prep(const float* __restrict__ X,
                                              const float* __restrict__ RC,
                                              const float* __restrict__ W,
                                              float* __restrict__ out,
                                              unsigned short* __restrict__ Xh,
                                              unsigned short* __restrict__ Wth) {
    if (blockIdx.x >= 8192) {
        // ---- split_w part: 128 blocks, W -> transposed fp16, tiled [n][k] ----
        int i = (blockIdx.x - 8192) * 256 + threadIdx.x;
        int n = i & 511;
        int k0 = (i >> 9) * 8;
        unsigned int hw[4];
#pragma unroll
        for (int e = 0; e < 4; ++e) {
            _Float16 h0 = (_Float16)W[(size_t)(k0 + 2 * e) * H_DIM + n];
            _Float16 h1 = (_Float16)W[(size_t)(k0 + 2 * e + 1) * H_DIM + n];
            hw[e] = (unsigned int)h_bits(h0) | ((unsigned int)h_bits(h1) << 16);
        }
        *(uint4*)(Wth + tiled_idx(n, k0)) = make_uint4(hw[0], hw[1], hw[2], hw[3]);
        return;
    }
    int i = blockIdx.x * 256 + threadIdx.x;
    int row = i >> 6;                 // t*B + b
    int h0 = (i & 63) * 8;
    int t = row >> 4;
    int b = row & 15;
    const float* xp = X + (size_t)row * H_DIM + h0;
    float4 v0 = *(const float4*)xp;
    float4 v1 = *(const float4*)(xp + 4);
    float* op = out + (size_t)row * (2 * H_DIM) + h0;
    *(float4*)op = v0;
    *(float4*)(op + 4) = v1;
    const float* cp = RC + (size_t)row * H_DIM + h0;
    float4 c0 = *(const float4*)cp;
    float4 c1 = *(const float4*)(cp + 4);
    if (t < 2) { c0 = v0; c1 = v1; }
    *(float4*)(op + H_DIM) = c0;
    *(float4*)(op + H_DIM + 4) = c1;
    float xs[8] = {v0.x, v0.y, v0.z, v0.w, v1.x, v1.y, v1.z, v1.w};
    unsigned int hw[4];
#pragma unroll
    for (int e = 0; e < 4; ++e) {
        _Float16 a = (_Float16)xs[2 * e], bb = (_Float16)xs[2 * e + 1];
        hw[e] = (unsigned int)h_bits(a) | ((unsigned int)h_bits(bb) << 16);
    }
    int r = b * T_DIM + t;            // batch-major row index
    *(uint4*)(Xh + tiled_idx(r, h0)) = make_uint4(hw[0], hw[1], hw[2], hw[3]);
}

// ---------- staging: half of a pre-tiled 8KB tile -> LDS, linear coalesced copy ----------
__device__ __forceinline__ void stage_half(const unsigned short* __restrict__ src_tile,
                                           unsigned short* lds_base, int lane, int h) {
#pragma unroll
    for (int c = 0; c < 4; ++c) {
        const int ch = h * 4 + c;
        __builtin_amdgcn_global_load_lds(
            (const __attribute__((address_space(1))) void*)(src_tile + ch * 512 + lane * 8),
            (__attribute__((address_space(3))) void*)(lds_base + ch * 512),
            16, 0, 0);
    }
}

// ---------- Kernel 2: Q = X @ W, single-pass fp16 MFMA, BK=64 (R10-proven) ----------
__global__ __launch_bounds__(256) void k_qgemm_mfma(const unsigned short* __restrict__ Xh,
                                                    const unsigned short* __restrict__ Wth,
                                                    unsigned short* __restrict__ Qh) {
    __shared__ __align__(16) unsigned short Ah[2][4][128][8], Bh[2][4][128][8];
    const int bid = blockIdx.x;                       // 1024 = 8 * 128
    const int swz = (bid & 7) * 128 + (bid >> 3);     // bijective
    const int mblk = swz >> 2, nblk = swz & 3;
    const int m0 = mblk * 128, n0 = nblk * 128;
    const int tid = threadIdx.x, lane = tid & 63, w = tid >> 6;
    const int t_off = (w >> 1) * 64, s_off = (w & 1) * 64;
    const int l15 = lane & 15, lg = lane >> 4;
    f32x4 acc[4][4] = {};

    for (int ksp = 0; ksp < NKB / 2; ++ksp) {
        if (ksp) __syncthreads();
        if (w < 2) {
            stage_half(Xh + tile_off(mblk, 2 * ksp),     &Ah[0][0][0][0], lane, w);
            stage_half(Xh + tile_off(mblk, 2 * ksp + 1), &Ah[1][0][0][0], lane, w);
        } else {
            stage_half(Wth + tile_off(nblk, 2 * ksp),     &Bh[0][0][0][0], lane, w - 2);
            stage_half(Wth + tile_off(nblk, 2 * ksp + 1), &Bh[1][0][0][0], lane, w - 2);
        }
        __syncthreads();

#pragma unroll
        for (int kk = 0; kk < 2; ++kk) {
            f16x8 ah[4], bh[4];
#pragma unroll
            for (int i2 = 0; i2 < 4; ++i2)
                ah[i2] = *(const f16x8*)&Ah[kk][lg][t_off + i2 * 16 + l15][0];
#pragma unroll
            for (int j = 0; j < 4; ++j)
                bh[j] = *(const f16x8*)&Bh[kk][lg][s_off + j * 16 + l15][0];
#pragma unroll
            for (int i2 = 0; i2 < 4; ++i2)
#pragma unroll
                for (int j = 0; j < 4; ++j)
                    acc[i2][j] = __builtin_amdgcn_mfma_f32_16x16x32_f16(ah[i2], bh[j], acc[i2][j], 0, 0, 0);
        }
    }

    // scatter epilogue (proven pattern), hi-only fp16 output
#pragma unroll
    for (int i2 = 0; i2 < 4; ++i2)
#pragma unroll
        for (int j = 0; j < 4; ++j)
#pragma unroll
            for (int r = 0; r < 4; ++r) {
                int R = m0 + t_off + i2 * 16 + lg * 4 + r;
                int C = n0 + s_off + j * 16 + l15;
                _Float16 qh = (_Float16)acc[i2][j][r];
                Qh[tiled_idx(R, C)] = h_bits(qh);
            }
}

// ---------- Kernel 3: scores, single-pass fp16 MFMA, BK=64, triangle + XCD swizzle ----------
__global__ __launch_bounds__(256) void k_scores_mfma(const unsigned short* __restrict__ Qh,
                                                     const unsigned short* __restrict__ Xh,
                                                     float* __restrict__ attn) {
    // 2176 live blocks = 16 batches x 136 triangle tile-pairs; 2176 = 8 * 272
    const int bid = blockIdx.x;
    const int swz = (bid & 7) * 272 + (bid >> 3);     // bijective XCD chunking
    const int b = swz / 136;
    const int r = swz - b * 136;
    int ti = (int)((sqrtf(8.f * (float)r + 1.f) - 1.f) * 0.5f);
    while ((ti + 1) * (ti + 2) / 2 <= r) ++ti;
    while (ti * (ti + 1) / 2 > r) --ti;
    const int si = r - ti * (ti + 1) / 2;             // si <= ti
    const int t0 = ti * 128, s0 = si * 128;

    __shared__ __align__(16) unsigned short Ah[2][4][128][8], Bh[2][4][128][8];
    const int tid = threadIdx.x, lane = tid & 63, w = tid >> 6;
    const int t_off = (w >> 1) * 64, s_off = (w & 1) * 64;
    const int l15 = lane & 15, lg = lane >> 4;
    const int ablk = b * (T_DIM / 128) + ti;
    const int bblk = b * (T_DIM / 128) + si;
    f32x4 acc[4][4] = {};

    for (int ksp = 0; ksp < NKB / 2; ++ksp) {
        if (ksp) __syncthreads();
        if (w < 2) {
            stage_half(Qh + tile_off(ablk, 2 * ksp),     &Ah[0][0][0][0], lane, w);
            stage_half(Qh + tile_off(ablk, 2 * ksp + 1), &Ah[1][0][0][0], lane, w);
        } else {
            stage_half(Xh + tile_off(bblk, 2 * ksp),     &Bh[0][0][0][0], lane, w - 2);
            stage_half(Xh + tile_off(bblk, 2 * ksp + 1), &Bh[1][0][0][0], lane, w - 2);
        }
        __syncthreads();

#pragma unroll
        for (int kk = 0; kk < 2; ++kk) {
            f16x8 ah[4], bh[4];
#pragma unroll
            for (int i2 = 0; i2 < 4; ++i2)
                ah[i2] = *(const f16x8*)&Ah[kk][lg][t_off + i2 * 16 + l15][0];
#pragma unroll
            for (int j = 0; j < 4; ++j)
                bh[j] = *(const f16x8*)&Bh[kk][lg][s_off + j * 16 + l15][0];
#pragma unroll
            for (int i2 = 0; i2 < 4; ++i2)
#pragma unroll
                for (int j = 0; j < 4; ++j)
                    acc[i2][j] = __builtin_amdgcn_mfma_f32_16x16x32_f16(ah[i2], bh[j], acc[i2][j], 0, 0, 0);
        }
    }

    float* base = attn + (size_t)b * T_DIM * T_DIM;
#pragma unroll
    for (int i2 = 0; i2 < 4; ++i2)
#pragma unroll
        for (int j = 0; j < 4; ++j)
#pragma unroll
            for (int rr = 0; rr < 4; ++rr) {
                int t = t0 + t_off + i2 * 16 + lg * 4 + rr;
                int s = s0 + s_off + j * 16 + l15;
                base[(size_t)t * T_DIM + s] = acc[i2][j][rr];
            }
}

// ---------- Kernel 4: in-place masked softmax, ONLINE max+sum (single read pass) ----------
__global__ __launch_bounds__(256) void k_softmax(float* __restrict__ attn) {
    const int row = blockIdx.x;
    const int t = row & (T_DIM - 1);
    float* p = attn + (size_t)row * T_DIM;
    const int tid = threadIdx.x;
    const int n = (t >= 2) ? t : 0;
    __shared__ float redm[4], redl[4];

    if (n == 0) {
        const float4 z = {0.f, 0.f, 0.f, 0.f};
        for (int s = tid * 4; s < T_DIM; s += 1024) *(float4*)&p[s] = z;
        return;
    }

    // online (m, l) over this thread's strided chunks, float4 reads
    float m = -1e30f, l = 0.f;
    for (int s = tid * 4; s < n; s += 1024) {
        float v[4];
        int cnt;
        if (s + 3 < n) {
            float4 q = *(const float4*)&p[s];
            v[0] = q.x; v[1] = q.y; v[2] = q.z; v[3] = q.w; cnt = 4;
        } else {
            cnt = n - s;
            for (int j = 0; j < cnt; ++j) v[j] = p[s + j];
        }
        float vm = v[0];
        for (int j = 1; j < cnt; ++j) vm = fmaxf(vm, v[j]);
        if (vm > m) { l *= expf(m - vm); m = vm; }
        for (int j = 0; j < cnt; ++j) l += expf(v[j] - m);
    }
    // wave-level merge of (m, l)
#pragma unroll
    for (int off = 32; off >= 1; off >>= 1) {
        float mo = __shfl_xor(m, off);
        float lo = __shfl_xor(l, off);
        float M = fmaxf(m, mo);
        l = l * expf(m - M) + lo * expf(mo - M);
        m = M;
    }
    if ((tid & 63) == 0) { redm[tid >> 6] = m; redl[tid >> 6] = l; }
    __syncthreads();
    {
        float M = fmaxf(fmaxf(redm[0], redm[1]), fmaxf(redm[2], redm[3]));
        float L = redl[0] * expf(redm[0] - M) + redl[1] * expf(redm[1] - M)
                + redl[2] * expf(redm[2] - M) + redl[3] * expf(redm[3] - M);
        m = M;
        l = L;
    }
    const float inv = 1.f / l;

    // write pass: probs for s < n, zeros elsewhere
    for (int s = tid * 4; s < T_DIM; s += 1024) {
        float4 o = {0.f, 0.f, 0.f, 0.f};
        if (s + 3 < n) {
            float4 v = *(float4*)&p[s];
            o.x = expf(v.x - m) * inv;
            o.y = expf(v.y - m) * inv;
            o.z = expf(v.z - m) * inv;
            o.w = expf(v.w - m) * inv;
        } else if (s < n) {
            float tmp[4] = {0.f, 0.f, 0.f, 0.f};
            for (int j = 0; j < 4; ++j)
                if (s + j < n) tmp[j] = expf(p[s + j] - m) * inv;
            o.x = tmp[0]; o.y = tmp[1]; o.z = tmp[2]; o.w = tmp[3];
        }
        *(float4*)&p[s] = o;
    }
}

extern "C" void kernel_launch(void* const* d_in, const int* in_sizes, int n_in,
                              void* d_out, int out_size, void* d_ws, size_t ws_size,
                              hipStream_t stream) {
    const float* inputs   = (const float*)d_in[0];   // [T,B,H]
    const float* rand_ctx = (const float*)d_in[1];   // [T,B,H]
    const float* W        = (const float*)d_in[2];   // [H,H]
    float* out  = (float*)d_out;
    float* attn = out + (size_t)T_DIM * B_DIM * 2 * H_DIM;

    unsigned short* Xh  = (unsigned short*)d_ws;
    unsigned short* Qh  = Xh + (size_t)33554432;
    unsigned short* Wth = Xh + (size_t)67108864;

    // prep (8192 blocks) + W transpose (128 tail blocks) in one dispatch
    k_prep<<<dim3(8192 + 128), dim3(256), 0, stream>>>(
        inputs, rand_ctx, W, out, Xh, Wth);

    k_qgemm_mfma<<<dim3(1024), dim3(256), 0, stream>>>(Xh, Wth, Qh);

    k_scores_mfma<<<dim3(2176), dim3(256), 0, stream>>>(Qh, Xh, attn);

    k_softmax<<<dim3(B_DIM * T_DIM), dim3(256), 0, stream>>>(attn);
}

// Round 13
// 293.552 us; speedup vs baseline: 1.0626x; 1.0508x over previous
//
#include <hip/hip_runtime.h>
#include <math.h>

#define T_DIM 2048
#define B_DIM 16
#define H_DIM 512
#define NKB   (H_DIM / 32)   // 16 k-blocks of 32
// out: results [T,B,2H] (33,554,432 f32) then attn [B,T,T] (67,108,864 f32)
// ws (ushort = fp16 bits), arrays TILED: tile(rowblk,kblk) = 8KB as [g(4)][row(128)][8]
//   Xh @0 (32MB), Qh @32Mi elems (32MB), Wth @64Mi elems (512KB).
// Raw scores: fp16, packed into the LOW HALF of each attn row (bytes [0,4096) of
// the row's 8KB), overwritten in-place by k_softmax's f32 output.

typedef _Float16 f16x8 __attribute__((ext_vector_type(8)));
typedef float f32x4 __attribute__((ext_vector_type(4)));

__device__ __forceinline__ unsigned short h_bits(_Float16 h) {
    unsigned short u; __builtin_memcpy(&u, &h, 2); return u;
}
__device__ __forceinline__ float h2f(unsigned short u) {
    _Float16 h; __builtin_memcpy(&h, &u, 2); return (float)h;
}

__device__ __forceinline__ size_t tile_off(int rowblk, int kblk) {
    return ((size_t)rowblk * NKB + kblk) * 4096;   // 4096 ushorts = 8KB per tile
}
__device__ __forceinline__ size_t tiled_idx(int r, int c) {
    return tile_off(r >> 7, c >> 5) + (size_t)((c >> 3) & 3) * 1024 + (size_t)(r & 127) * 8 + (c & 7);
}

// ---------- Kernel 1: results copy + X -> fp16 (tiled) ; tail blocks: W transpose ----------
__global__ __launch_bounds__(256) void k_prep(const float* __restrict__ X,
                                              const float* __restrict__ RC,
                                              const float* __restrict__ W,
                                              float* __restrict__ out,
                                              unsigned short* __restrict__ Xh,
                                              unsigned short* __restrict__ Wth) {
    if (blockIdx.x >= 8192) {
        // ---- split_w part: 128 blocks, W -> transposed fp16, tiled [n][k] ----
        int i = (blockIdx.x - 8192) * 256 + threadIdx.x;
        int n = i & 511;
        int k0 = (i >> 9) * 8;
        unsigned int hw[4];
#pragma unroll
        for (int e = 0; e < 4; ++e) {
            _Float16 h0 = (_Float16)W[(size_t)(k0 + 2 * e) * H_DIM + n];
            _Float16 h1 = (_Float16)W[(size_t)(k0 + 2 * e + 1) * H_DIM + n];
            hw[e] = (unsigned int)h_bits(h0) | ((unsigned int)h_bits(h1) << 16);
        }
        *(uint4*)(Wth + tiled_idx(n, k0)) = make_uint4(hw[0], hw[1], hw[2], hw[3]);
        return;
    }
    int i = blockIdx.x * 256 + threadIdx.x;
    int row = i >> 6;                 // t*B + b
    int h0 = (i & 63) * 8;
    int t = row >> 4;
    int b = row & 15;
    const float* xp = X + (size_t)row * H_DIM + h0;
    float4 v0 = *(const float4*)xp;
    float4 v1 = *(const float4*)(xp + 4);
    float* op = out + (size_t)row * (2 * H_DIM) + h0;
    *(float4*)op = v0;
    *(float4*)(op + 4) = v1;
    const float* cp = RC + (size_t)row * H_DIM + h0;
    float4 c0 = *(const float4*)cp;
    float4 c1 = *(const float4*)(cp + 4);
    if (t < 2) { c0 = v0; c1 = v1; }
    *(float4*)(op + H_DIM) = c0;
    *(float4*)(op + H_DIM + 4) = c1;
    float xs[8] = {v0.x, v0.y, v0.z, v0.w, v1.x, v1.y, v1.z, v1.w};
    unsigned int hw[4];
#pragma unroll
    for (int e = 0; e < 4; ++e) {
        _Float16 a = (_Float16)xs[2 * e], bb = (_Float16)xs[2 * e + 1];
        hw[e] = (unsigned int)h_bits(a) | ((unsigned int)h_bits(bb) << 16);
    }
    int r = b * T_DIM + t;            // batch-major row index
    *(uint4*)(Xh + tiled_idx(r, h0)) = make_uint4(hw[0], hw[1], hw[2], hw[3]);
}

// ---------- staging: half of a pre-tiled 8KB tile -> LDS, linear coalesced copy ----------
__device__ __forceinline__ void stage_half(const unsigned short* __restrict__ src_tile,
                                           unsigned short* lds_base, int lane, int h) {
#pragma unroll
    for (int c = 0; c < 4; ++c) {
        const int ch = h * 4 + c;
        __builtin_amdgcn_global_load_lds(
            (const __attribute__((address_space(1))) void*)(src_tile + ch * 512 + lane * 8),
            (__attribute__((address_space(3))) void*)(lds_base + ch * 512),
            16, 0, 0);
    }
}

// ---------- Kernel 2: Q = X @ W, single-pass fp16 MFMA, BK=64 (R10-proven) ----------
__global__ __launch_bounds__(256) void k_qgemm_mfma(const unsigned short* __restrict__ Xh,
                                                    const unsigned short* __restrict__ Wth,
                                                    unsigned short* __restrict__ Qh) {
    __shared__ __align__(16) unsigned short Ah[2][4][128][8], Bh[2][4][128][8];
    const int bid = blockIdx.x;                       // 1024 = 8 * 128
    const int swz = (bid & 7) * 128 + (bid >> 3);     // bijective
    const int mblk = swz >> 2, nblk = swz & 3;
    const int m0 = mblk * 128, n0 = nblk * 128;
    const int tid = threadIdx.x, lane = tid & 63, w = tid >> 6;
    const int t_off = (w >> 1) * 64, s_off = (w & 1) * 64;
    const int l15 = lane & 15, lg = lane >> 4;
    f32x4 acc[4][4] = {};

    for (int ksp = 0; ksp < NKB / 2; ++ksp) {
        if (ksp) __syncthreads();
        if (w < 2) {
            stage_half(Xh + tile_off(mblk, 2 * ksp),     &Ah[0][0][0][0], lane, w);
            stage_half(Xh + tile_off(mblk, 2 * ksp + 1), &Ah[1][0][0][0], lane, w);
        } else {
            stage_half(Wth + tile_off(nblk, 2 * ksp),     &Bh[0][0][0][0], lane, w - 2);
            stage_half(Wth + tile_off(nblk, 2 * ksp + 1), &Bh[1][0][0][0], lane, w - 2);
        }
        __syncthreads();

#pragma unroll
        for (int kk = 0; kk < 2; ++kk) {
            f16x8 ah[4], bh[4];
#pragma unroll
            for (int i2 = 0; i2 < 4; ++i2)
                ah[i2] = *(const f16x8*)&Ah[kk][lg][t_off + i2 * 16 + l15][0];
#pragma unroll
            for (int j = 0; j < 4; ++j)
                bh[j] = *(const f16x8*)&Bh[kk][lg][s_off + j * 16 + l15][0];
#pragma unroll
            for (int i2 = 0; i2 < 4; ++i2)
#pragma unroll
                for (int j = 0; j < 4; ++j)
                    acc[i2][j] = __builtin_amdgcn_mfma_f32_16x16x32_f16(ah[i2], bh[j], acc[i2][j], 0, 0, 0);
        }
    }

    // scatter epilogue (proven pattern), hi-only fp16 output
#pragma unroll
    for (int i2 = 0; i2 < 4; ++i2)
#pragma unroll
        for (int j = 0; j < 4; ++j)
#pragma unroll
            for (int r = 0; r < 4; ++r) {
                int R = m0 + t_off + i2 * 16 + lg * 4 + r;
                int C = n0 + s_off + j * 16 + l15;
                _Float16 qh = (_Float16)acc[i2][j][r];
                Qh[tiled_idx(R, C)] = h_bits(qh);
            }
}

// ---------- Kernel 3: scores, single-pass fp16 MFMA; RAW fp16 into low half of row ----------
__global__ __launch_bounds__(256) void k_scores_mfma(const unsigned short* __restrict__ Qh,
                                                     const unsigned short* __restrict__ Xh,
                                                     float* __restrict__ attn) {
    // 2176 live blocks = 16 batches x 136 triangle tile-pairs; 2176 = 8 * 272
    const int bid = blockIdx.x;
    const int swz = (bid & 7) * 272 + (bid >> 3);     // bijective XCD chunking
    const int b = swz / 136;
    const int r = swz - b * 136;
    int ti = (int)((sqrtf(8.f * (float)r + 1.f) - 1.f) * 0.5f);
    while ((ti + 1) * (ti + 2) / 2 <= r) ++ti;
    while (ti * (ti + 1) / 2 > r) --ti;
    const int si = r - ti * (ti + 1) / 2;             // si <= ti
    const int t0 = ti * 128, s0 = si * 128;

    __shared__ __align__(16) unsigned short Ah[2][4][128][8], Bh[2][4][128][8];
    const int tid = threadIdx.x, lane = tid & 63, w = tid >> 6;
    const int t_off = (w >> 1) * 64, s_off = (w & 1) * 64;
    const int l15 = lane & 15, lg = lane >> 4;
    const int ablk = b * (T_DIM / 128) + ti;
    const int bblk = b * (T_DIM / 128) + si;
    f32x4 acc[4][4] = {};

    for (int ksp = 0; ksp < NKB / 2; ++ksp) {
        if (ksp) __syncthreads();
        if (w < 2) {
            stage_half(Qh + tile_off(ablk, 2 * ksp),     &Ah[0][0][0][0], lane, w);
            stage_half(Qh + tile_off(ablk, 2 * ksp + 1), &Ah[1][0][0][0], lane, w);
        } else {
            stage_half(Xh + tile_off(bblk, 2 * ksp),     &Bh[0][0][0][0], lane, w - 2);
            stage_half(Xh + tile_off(bblk, 2 * ksp + 1), &Bh[1][0][0][0], lane, w - 2);
        }
        __syncthreads();

#pragma unroll
        for (int kk = 0; kk < 2; ++kk) {
            f16x8 ah[4], bh[4];
#pragma unroll
            for (int i2 = 0; i2 < 4; ++i2)
                ah[i2] = *(const f16x8*)&Ah[kk][lg][t_off + i2 * 16 + l15][0];
#pragma unroll
            for (int j = 0; j < 4; ++j)
                bh[j] = *(const f16x8*)&Bh[kk][lg][s_off + j * 16 + l15][0];
#pragma unroll
            for (int i2 = 0; i2 < 4; ++i2)
#pragma unroll
                for (int j = 0; j < 4; ++j)
                    acc[i2][j] = __builtin_amdgcn_mfma_f32_16x16x32_f16(ah[i2], bh[j], acc[i2][j], 0, 0, 0);
        }
    }

    // raw scores as fp16 packed into the row's low half: ushort[s] at row base
    float* base = attn + (size_t)b * T_DIM * T_DIM;
#pragma unroll
    for (int i2 = 0; i2 < 4; ++i2)
#pragma unroll
        for (int j = 0; j < 4; ++j)
#pragma unroll
            for (int rr = 0; rr < 4; ++rr) {
                int t = t0 + t_off + i2 * 16 + lg * 4 + rr;
                int s = s0 + s_off + j * 16 + l15;
                _Float16 hv = (_Float16)acc[i2][j][rr];
                ((unsigned short*)(base + (size_t)t * T_DIM))[s] = h_bits(hv);
            }
}

// ---------- Kernel 4: masked softmax; fp16-raw read (1 uint4/thread), f32 write ----------
// 256 threads x 8 contiguous elems. All raw reads complete before the merge
// __syncthreads(); all f32 writes (which clobber the raw bytes) happen after.
__global__ __launch_bounds__(256) void k_softmax(float* __restrict__ attn) {
    const int row = blockIdx.x;
    const int t = row & (T_DIM - 1);
    float* p = attn + (size_t)row * T_DIM;
    const int tid = threadIdx.x;
    const int n = (t >= 2) ? t : 0;
    __shared__ float redm[4], redl[4];

    if (n == 0) {
        const float4 z = {0.f, 0.f, 0.f, 0.f};
        *(float4*)&p[tid * 8] = z;
        *(float4*)&p[tid * 8 + 4] = z;
        return;
    }

    // read this thread's 8 raw fp16 scores (coalesced uint4)
    const int sbase = tid * 8;
    uint4 rv = *(const uint4*)((const unsigned short*)p + sbase);
    float v[8];
    v[0] = h2f((unsigned short)(rv.x & 0xffff)); v[1] = h2f((unsigned short)(rv.x >> 16));
    v[2] = h2f((unsigned short)(rv.y & 0xffff)); v[3] = h2f((unsigned short)(rv.y >> 16));
    v[4] = h2f((unsigned short)(rv.z & 0xffff)); v[5] = h2f((unsigned short)(rv.z >> 16));
    v[6] = h2f((unsigned short)(rv.w & 0xffff)); v[7] = h2f((unsigned short)(rv.w >> 16));

    float m = -1e30f, l = 0.f;
#pragma unroll
    for (int j = 0; j < 8; ++j)
        if (sbase + j < n) m = fmaxf(m, v[j]);
#pragma unroll
    for (int j = 0; j < 8; ++j)
        if (sbase + j < n) l += expf(v[j] - m);

    // wave butterfly merge of (m, l)
#pragma unroll
    for (int off = 1; off <= 32; off <<= 1) {
        float mo = __shfl_xor(m, off);
        float lo = __shfl_xor(l, off);
        float M = fmaxf(m, mo);
        l = l * expf(m - M) + lo * expf(mo - M);
        m = M;
    }
    if ((tid & 63) == 0) { redm[tid >> 6] = m; redl[tid >> 6] = l; }
    __syncthreads();   // also fences raw-reads before f32 writes below
    {
        float M = fmaxf(fmaxf(redm[0], redm[1]), fmaxf(redm[2], redm[3]));
        float L = redl[0] * expf(redm[0] - M) + redl[1] * expf(redm[1] - M)
                + redl[2] * expf(redm[2] - M) + redl[3] * expf(redm[3] - M);
        m = M;
        l = L;
    }
    const float inv = 1.f / l;

    float o[8];
#pragma unroll
    for (int j = 0; j < 8; ++j)
        o[j] = (sbase + j < n) ? expf(v[j] - m) * inv : 0.f;
    float4 o0 = {o[0], o[1], o[2], o[3]};
    float4 o1 = {o[4], o[5], o[6], o[7]};
    *(float4*)&p[sbase] = o0;
    *(float4*)&p[sbase + 4] = o1;
}

extern "C" void kernel_launch(void* const* d_in, const int* in_sizes, int n_in,
                              void* d_out, int out_size, void* d_ws, size_t ws_size,
                              hipStream_t stream) {
    const float* inputs   = (const float*)d_in[0];   // [T,B,H]
    const float* rand_ctx = (const float*)d_in[1];   // [T,B,H]
    const float* W        = (const float*)d_in[2];   // [H,H]
    float* out  = (float*)d_out;
    float* attn = out + (size_t)T_DIM * B_DIM * 2 * H_DIM;

    unsigned short* Xh  = (unsigned short*)d_ws;
    unsigned short* Qh  = Xh + (size_t)33554432;
    unsigned short* Wth = Xh + (size_t)67108864;

    // prep (8192 blocks) + W transpose (128 tail blocks) in one dispatch
    k_prep<<<dim3(8192 + 128), dim3(256), 0, stream>>>(
        inputs, rand_ctx, W, out, Xh, Wth);

    k_qgemm_mfma<<<dim3(1024), dim3(256), 0, stream>>>(Xh, Wth, Qh);

    k_scores_mfma<<<dim3(2176), dim3(256), 0, stream>>>(Qh, Xh, attn);

    k_softmax<<<dim3(B_DIM * T_DIM), dim3(256), 0, stream>>>(attn);
}